// Round 2
// baseline (219.866 us; speedup 1.0000x reference)
//
#include <hip/hip_runtime.h>

// Destroy operator: y = (U kron I2) @ x where U[i,i+1] = sqrt(i+1).
// Reduces to: out[r, :] = sqrt(r/2 + 1) * x[r+2, :] for r < 2D-2; last 2 rows = 0.
// x: (2D, B) fp32 row-major, D = 4096, B = 4096.
//
// R5 (resubmit — previous round failed on container acquisition, not kernel):
// pair-merged streaming. Each block owns TWO adjacent row-pairs
// (pA = 2*blockIdx.x, pB = pA+1): 2048 blocks = exactly 8 blocks/CU (one
// occupancy batch), 64 KB read + 64 KB write per block, and 16 outstanding
// global_load_dwordx4 per wave before the first store issues (was 8).
// Theory: kernel slice of dur_us is ~56 us = 4.8 TB/s, vs 6.3 TB/s copy
// ceiling -- shallow MLP + short-lived blocks are the suspected gap.
//
// Zero tail (pair D-1) is handled WITHOUT divergence or OOB reads:
// its coefficient is 0 and its source address is clamped in-bounds, so it
// streams its own pair and writes 0*finite = 0. Block-uniform select only.

typedef float vf4 __attribute__((ext_vector_type(4)));

constexpr int kD = 4096;
constexpr int kB = 4096;
constexpr int kV4Row  = kB / 4;        // 1024 float4 per row
constexpr int kV4Pair = 2 * kV4Row;    // 2048 float4 per row-pair
constexpr int kPT     = 8;             // float4 per thread per row-pair (2048/256)

__global__ __launch_bounds__(256) void destroy_kernel(
    const vf4* __restrict__ x, vf4* __restrict__ y) {
    const int t  = threadIdx.x;
    const int pA = blockIdx.x * 2;     // row-pair indices: pA, pA+1
    const int pB = pA + 1;

    const int baseA = pA * kV4Pair + t;
    const int baseB = pB * kV4Pair + t;

    // Last row-pair writes zeros: coefficient 0, source clamped in-bounds.
    const bool  lastB = (pB == kD - 1);
    const float cA = sqrtf((float)(pA + 1));
    const float cB = lastB ? 0.f : sqrtf((float)(pB + 1));
    const int   srcB = lastB ? baseB : (baseB + kV4Pair);

    vf4 va[kPT], vb[kPT];
    // 16 loads in flight per thread before any store.
#pragma unroll
    for (int j = 0; j < kPT; ++j)
        va[j] = __builtin_nontemporal_load(&x[baseA + kV4Pair + j * 256]);
#pragma unroll
    for (int j = 0; j < kPT; ++j)
        vb[j] = __builtin_nontemporal_load(&x[srcB + j * 256]);

#pragma unroll
    for (int j = 0; j < kPT; ++j)
        __builtin_nontemporal_store(cA * va[j], &y[baseA + j * 256]);
#pragma unroll
    for (int j = 0; j < kPT; ++j)
        __builtin_nontemporal_store(cB * vb[j], &y[baseB + j * 256]);
}

extern "C" void kernel_launch(void* const* d_in, const int* in_sizes, int n_in,
                              void* d_out, int out_size, void* d_ws, size_t ws_size,
                              hipStream_t stream) {
    const vf4* x = (const vf4*)d_in[0];
    vf4* y = (vf4*)d_out;
    destroy_kernel<<<dim3(kD / 2), dim3(256), 0, stream>>>(x, y);
}